// Round 4
// baseline (1239.710 us; speedup 1.0000x reference)
//
#include <hip/hip_runtime.h>
#include <math.h>

constexpr int Bn = 256, Sn = 128, Hn = 256;
constexpr int GRP = 8;   // 8 s-rows per group: keeps per-thread live set < 128 VGPRs

// ---------------- setup: branch kernels k_i[h,tau] = irfft(w_i[h,:]) ----------------
// kT layout: [24][H]  slots: n=3 -> 0..2, n=5 -> 3..7, n=7 -> 8..14, n=9 -> 15..23
__global__ void k_setup(const float* __restrict__ w3, const float* __restrict__ w5,
                        const float* __restrict__ w7, const float* __restrict__ w9,
                        float* __restrict__ kT) {
  int t = blockIdx.x * blockDim.x + threadIdx.x;
  if (t >= 24 * Hn) return;
  int slot = t >> 8, h = t & 255;
  int n, base;
  const float* w;
  if (slot < 3)       { n = 3; base = 0;  w = w3; }
  else if (slot < 8)  { n = 5; base = 3;  w = w5; }
  else if (slot < 15) { n = 7; base = 8;  w = w7; }
  else                { n = 9; base = 15; w = w9; }
  int tau = slot - base;
  int F = (n + 1) / 2;
  float acc = w[(h * F) * 2];  // DC real (imag of DC cannot affect real output)
  for (int f = 1; f < F; f++) {
    float wr = w[(h * F + f) * 2 + 0];
    float wi = w[(h * F + f) * 2 + 1];
    int ft = (f * tau) % n;
    float ang = 6.28318530717958647692f * (float)ft / (float)n;
    float sv, cv;
    __sincosf(ang, &sv, &cv);
    acc += 2.f * (wr * cv - wi * sv);
  }
  kT[slot * Hn + h] = acc / (float)n;
}

// ---------------- setup: fft-branch circular kernel c[h,d] = irfft(cw[:,h]) ----------------
// cT layout: [128][H]  (d-major so lane reads over h are coalesced)
__global__ void c_setup(const float* __restrict__ cw, float* __restrict__ cT) {
  int t = blockIdx.x * blockDim.x + threadIdx.x;
  if (t >= Sn * Hn) return;
  int d = t >> 8, h = t & 255;
  float acc = cw[(0 * Hn + h) * 2 + 0] + ((d & 1) ? -1.f : 1.f) * cw[(64 * Hn + h) * 2 + 0];
  for (int k = 1; k < 64; k++) {
    float wr = cw[(k * Hn + h) * 2 + 0];
    float wi = cw[(k * Hn + h) * 2 + 1];
    int kd = (k * d) & 127;
    float ang = 6.28318530717958647692f * (float)kd * (1.f / 128.f);
    float sv, cv;
    __sincosf(ang, &sv, &cv);
    acc += 2.f * (wr * cv - wi * sv);
  }
  cT[d * Hn + h] = acc * (1.f / 128.f);
}

// ---------------- DPP wave reduction (VALU pipe, not DS) ----------------
// All DPP controls must be integer-constant expressions -> template params.
template <int CTRL, int ROW_MASK>
__device__ __forceinline__ float dpp_add_f32(float v) {
  int p = __builtin_amdgcn_update_dpp(0, __float_as_int(v), CTRL, ROW_MASK, 0xf, true);
  return v + __int_as_float(p);
}
__device__ __forceinline__ float wave_red_sum(float v) {
  v = dpp_add_f32<0x111, 0xf>(v); // row_shr:1
  v = dpp_add_f32<0x112, 0xf>(v); // row_shr:2
  v = dpp_add_f32<0x114, 0xf>(v); // row_shr:4
  v = dpp_add_f32<0x118, 0xf>(v); // row_shr:8  -> lane15 of each row-16 has row sum
  v = dpp_add_f32<0x142, 0xa>(v); // row_bcast:15 -> lanes 31 and 63 accumulate
  v = dpp_add_f32<0x143, 0xc>(v); // row_bcast:31 -> lane63 has wave sum
  return v;                       // lane 63 = full wave sum
}

// ---------------- STFT branch accumulation (taps + overlap-add geometry) ----------------
template <int N, int BASE>
__device__ __attribute__((always_inline)) void branch_accum(
    const float (&xw)[GRP + 16], const float (&kreg)[24], int s0, bool edge, float (&z)[GRP]) {
  constexpr int PAD = (N - 1) / 2;
  #pragma unroll
  for (int i = 0; i < GRP; i++) z[i] = 0.f;
  #pragma unroll
  for (int j = -(N - 1); j <= N - 1; j++) {
    const int m = (((-j) % N) + N) % N;   // folded at compile time under unroll
    const float kc = kreg[BASE + m];
    if (!edge) {
      const float ka = kc * ((float)(N - (j < 0 ? -j : j)) * (1.f / (float)N));
      #pragma unroll
      for (int i = 0; i < GRP; i++) z[i] = fmaf(ka, xw[8 + i + j], z[i]);
    } else {
      #pragma unroll
      for (int i = 0; i < GRP; i++) {
        int s = s0 + i, l = s + PAD;
        int tlo = max(0, max(l - Sn + 1, -j));
        int thi = min(N - 1, min(l, N - 1 - j));
        int cnt = max(0, thi - tlo + 1);
        int elo = max(0, l - Sn + 1), ehi = min(N - 1, l);
        float env = (float)(ehi - elo + 1);
        z[i] = fmaf(kc * ((float)cnt / env), xw[8 + i + j], z[i]);
      }
    }
  }
}

// ---------------- fused main kernel: one block per batch b ----------------
__global__ __launch_bounds__(512) void stft_main(
    const float* __restrict__ x, const float* __restrict__ cT,
    const float* __restrict__ kT, const float* __restrict__ lnw,
    const float* __restrict__ lnb, const float* __restrict__ alphap,
    float* __restrict__ out) {
  __shared__ float xs[Sn][Hn];          // 131072 B
  __shared__ float red[2][GRP][4][2];   // 512 B  cross-wave LN partials

  const int t = threadIdx.x;
  const int h = t & 255;
  const int sg = t >> 8;       // which s-half (0: s 0..63, 1: s 64..127)
  const int wv = h >> 6;       // wave within half
  const int lane = h & 63;
  const int b = blockIdx.x;

  // stage x[b] into LDS (coalesced float4)
  {
    const float4* xg = (const float4*)(x + (size_t)b * Sn * Hn);
    float4* xl = (float4*)(&xs[0][0]);
    #pragma unroll
    for (int c = 0; c < 16; c++) xl[c * 512 + t] = xg[c * 512 + t];
  }
  const float alpha = alphap[0];
  const float wgt = lnw[h], bia = lnb[h];
  float kreg[24];
  #pragma unroll
  for (int q = 0; q < 24; q++) kreg[q] = kT[q * Hn + h];
  __syncthreads();

  // LN stats over h (256) for GRP s-rows; normalizes in place (no affine).
  auto reduce_ln_raw = [&](float (&q)[GRP]) {
    #pragma unroll
    for (int i = 0; i < GRP; i++) {
      float s1 = wave_red_sum(q[i]);
      float s2 = wave_red_sum(q[i] * q[i]);
      if (lane == 63) { red[sg][i][wv][0] = s1; red[sg][i][wv][1] = s2; }
    }
    __syncthreads();
    #pragma unroll
    for (int i = 0; i < GRP; i++) {
      const float4* rp = (const float4*)&red[sg][i][0][0];
      float4 p0 = rp[0], p1 = rp[1];
      float ts = p0.x + p0.z + p1.x + p1.z;
      float tq = p0.y + p0.w + p1.y + p1.w;
      float u = ts * (1.f / 256.f);
      float var = fmaf(-u, u, tq * (1.f / 256.f));
      float inv = 1.f / sqrtf(var + 1e-12f);
      q[i] = (q[i] - u) * inv;   // normalized, no affine
    }
    __syncthreads();
  };

  for (int g = 0; g < 8; g++) {
    const int s0 = sg * 64 + g * GRP;
    const bool edge = (s0 == 0) || (s0 + GRP == Sn);

    // x window rows s0-8 .. s0+15 (zero-padded like reference's u)
    float xw[GRP + 16];
    #pragma unroll
    for (int k = 0; k < GRP + 16; k++) {
      int r = s0 - 8 + k;
      xw[k] = (r >= 0 && r < Sn) ? xs[r][h] : 0.f;
    }

    // ---- four STFT branches, each layernormed (raw) then summed ----
    float semb[GRP];
    {
      float z[GRP];
      branch_accum<3, 0>(xw, kreg, s0, edge, z);
      reduce_ln_raw(z);
      #pragma unroll
      for (int i = 0; i < GRP; i++) semb[i] = z[i];
      branch_accum<5, 3>(xw, kreg, s0, edge, z);
      reduce_ln_raw(z);
      #pragma unroll
      for (int i = 0; i < GRP; i++) semb[i] += z[i];
      branch_accum<7, 8>(xw, kreg, s0, edge, z);
      reduce_ln_raw(z);
      #pragma unroll
      for (int i = 0; i < GRP; i++) semb[i] += z[i];
      branch_accum<9, 15>(xw, kreg, s0, edge, z);
      reduce_ln_raw(z);
      #pragma unroll
      for (int i = 0; i < GRP; i++) semb[i] += z[i];
    }

    // ---- global-fft branch: circular conv, block-Toeplitz 8x16 tiles ----
    float ff[GRP];
    #pragma unroll
    for (int i = 0; i < GRP; i++) ff[i] = 0.f;
    #pragma unroll
    for (int rt = 0; rt < 8; rt++) {
      const int r0 = rt * 16;
      const int dbase = (s0 - r0) & 127;
      float cd[GRP + 15];
      #pragma unroll
      for (int k = 0; k < GRP + 15; k++)
        cd[k] = cT[((dbase + k - 15) & 127) * Hn + h];
      float xr[16];
      #pragma unroll
      for (int j = 0; j < 16; j++) xr[j] = xs[r0 + j][h];
      #pragma unroll
      for (int i = 0; i < GRP; i++) {
        #pragma unroll
        for (int j = 0; j < 16; j++)
          ff[i] = fmaf(cd[i - j + 15], xr[j], ff[i]);
      }
    }
    reduce_ln_raw(ff);

    // ---- mix + residual + final LN + store ----
    // sum_i LN_i = w*S + 4b ; LN_fft = w*F + b
    // mixed = w*(alpha*S + (1-alpha)*F) + b*(1+3*alpha) + x
    float fin[GRP];
    #pragma unroll
    for (int i = 0; i < GRP; i++) {
      float mixv = fmaf(alpha, semb[i] - ff[i], ff[i]);   // alpha*S + (1-alpha)*F
      fin[i] = fmaf(wgt, mixv, fmaf(3.f * alpha + 1.f, bia, xs[s0 + i][h]));
    }
    reduce_ln_raw(fin);
    #pragma unroll
    for (int i = 0; i < GRP; i++)
      out[((size_t)b * Sn + (s0 + i)) * Hn + h] = fmaf(fin[i], wgt, bia);
  }
}

extern "C" void kernel_launch(void* const* d_in, const int* in_sizes, int n_in,
                              void* d_out, int out_size, void* d_ws, size_t ws_size,
                              hipStream_t stream) {
  const float* x  = (const float*)d_in[0];
  const float* w3 = (const float*)d_in[1];
  const float* w5 = (const float*)d_in[2];
  const float* w7 = (const float*)d_in[3];
  const float* w9 = (const float*)d_in[4];
  const float* cw = (const float*)d_in[5];
  const float* al = (const float*)d_in[6];
  const float* lw = (const float*)d_in[7];
  const float* lb = (const float*)d_in[8];
  float* out = (float*)d_out;

  float* cT = (float*)d_ws;        // 128*256 floats
  float* kT = cT + Sn * Hn;        // 24*256 floats

  hipLaunchKernelGGL(k_setup, dim3(24), dim3(256), 0, stream, w3, w5, w7, w9, kT);
  hipLaunchKernelGGL(c_setup, dim3(Sn), dim3(256), 0, stream, cw, cT);
  hipLaunchKernelGGL(stft_main, dim3(Bn), dim3(512), 0, stream, x, cT, kT, lw, lb, al, out);
}

// Round 5
// 423.406 us; speedup vs baseline: 2.9279x; 2.9279x over previous
//
#include <hip/hip_runtime.h>
#include <math.h>

constexpr int Bn = 256, Sn = 128, Hn = 256;
constexpr int GRP = 8;   // 8 s-rows per group

// ---------------- setup: branch kernels k_i[h,tau] = irfft(w_i[h,:]) ----------------
// kT layout: [24][H]  slots: n=3 -> 0..2, n=5 -> 3..7, n=7 -> 8..14, n=9 -> 15..23
__global__ void k_setup(const float* __restrict__ w3, const float* __restrict__ w5,
                        const float* __restrict__ w7, const float* __restrict__ w9,
                        float* __restrict__ kT) {
  int t = blockIdx.x * blockDim.x + threadIdx.x;
  if (t >= 24 * Hn) return;
  int slot = t >> 8, h = t & 255;
  int n, base;
  const float* w;
  if (slot < 3)       { n = 3; base = 0;  w = w3; }
  else if (slot < 8)  { n = 5; base = 3;  w = w5; }
  else if (slot < 15) { n = 7; base = 8;  w = w7; }
  else                { n = 9; base = 15; w = w9; }
  int tau = slot - base;
  int F = (n + 1) / 2;
  float acc = w[(h * F) * 2];  // DC real (imag of DC cannot affect real output)
  for (int f = 1; f < F; f++) {
    float wr = w[(h * F + f) * 2 + 0];
    float wi = w[(h * F + f) * 2 + 1];
    int ft = (f * tau) % n;
    float ang = 6.28318530717958647692f * (float)ft / (float)n;
    float sv, cv;
    __sincosf(ang, &sv, &cv);
    acc += 2.f * (wr * cv - wi * sv);
  }
  kT[slot * Hn + h] = acc / (float)n;
}

// ---------------- setup: fft-branch circular kernel c[h,d] = irfft(cw[:,h]) ----------------
// cT layout: [128][H]  (d-major so lane reads over h are coalesced)
__global__ void c_setup(const float* __restrict__ cw, float* __restrict__ cT) {
  int t = blockIdx.x * blockDim.x + threadIdx.x;
  if (t >= Sn * Hn) return;
  int d = t >> 8, h = t & 255;
  float acc = cw[(0 * Hn + h) * 2 + 0] + ((d & 1) ? -1.f : 1.f) * cw[(64 * Hn + h) * 2 + 0];
  for (int k = 1; k < 64; k++) {
    float wr = cw[(k * Hn + h) * 2 + 0];
    float wi = cw[(k * Hn + h) * 2 + 1];
    int kd = (k * d) & 127;
    float ang = 6.28318530717958647692f * (float)kd * (1.f / 128.f);
    float sv, cv;
    __sincosf(ang, &sv, &cv);
    acc += 2.f * (wr * cv - wi * sv);
  }
  cT[d * Hn + h] = acc * (1.f / 128.f);
}

// ---------------- DPP wave reduction (VALU pipe, not DS) ----------------
template <int CTRL, int ROW_MASK>
__device__ __forceinline__ float dpp_add_f32(float v) {
  int p = __builtin_amdgcn_update_dpp(0, __float_as_int(v), CTRL, ROW_MASK, 0xf, true);
  return v + __int_as_float(p);
}
__device__ __forceinline__ float wave_red_sum(float v) {
  v = dpp_add_f32<0x111, 0xf>(v); // row_shr:1
  v = dpp_add_f32<0x112, 0xf>(v); // row_shr:2
  v = dpp_add_f32<0x114, 0xf>(v); // row_shr:4
  v = dpp_add_f32<0x118, 0xf>(v); // row_shr:8
  v = dpp_add_f32<0x142, 0xa>(v); // row_bcast:15
  v = dpp_add_f32<0x143, 0xc>(v); // row_bcast:31
  return v;                       // lane 63 = full wave sum
}

// ---------------- STFT branch accumulation (taps + overlap-add geometry) ----------------
template <int N, int BASE>
__device__ __attribute__((always_inline)) void branch_accum(
    const float (&xw)[GRP + 16], const float (&kreg)[24], int s0, bool edge, float (&z)[GRP]) {
  constexpr int PAD = (N - 1) / 2;
  #pragma unroll
  for (int i = 0; i < GRP; i++) z[i] = 0.f;
  #pragma unroll
  for (int j = -(N - 1); j <= N - 1; j++) {
    const int m = (((-j) % N) + N) % N;   // folded at compile time under unroll
    const float kc = kreg[BASE + m];
    if (!edge) {
      const float ka = kc * ((float)(N - (j < 0 ? -j : j)) * (1.f / (float)N));
      #pragma unroll
      for (int i = 0; i < GRP; i++) z[i] = fmaf(ka, xw[8 + i + j], z[i]);
    } else {
      #pragma unroll
      for (int i = 0; i < GRP; i++) {
        int s = s0 + i, l = s + PAD;
        int tlo = max(0, max(l - Sn + 1, -j));
        int thi = min(N - 1, min(l, N - 1 - j));
        int cnt = max(0, thi - tlo + 1);
        int elo = max(0, l - Sn + 1), ehi = min(N - 1, l);
        float env = (float)(ehi - elo + 1);
        z[i] = fmaf(kc * ((float)cnt / env), xw[8 + i + j], z[i]);
      }
    }
  }
}

// ---------------- fused main kernel: one block per batch b ----------------
// LDS (129KB) caps occupancy at 1 block/CU = 2 waves/EU. amdgpu_waves_per_eu(1,2)
// lifts the backend's default 4-waves/EU VGPR cap (128) so the live set fits in
// registers instead of spilling to scratch (R2/R4 showed 0.5-1.1 GB phantom HBM).
__global__ __launch_bounds__(512) __attribute__((amdgpu_waves_per_eu(1, 2)))
void stft_main(
    const float* __restrict__ x, const float* __restrict__ cT,
    const float* __restrict__ kT, const float* __restrict__ lnw,
    const float* __restrict__ lnb, const float* __restrict__ alphap,
    float* __restrict__ out) {
  __shared__ float xs[Sn][Hn];          // 131072 B
  __shared__ float red[2][GRP][4][2];   // 512 B  cross-wave LN partials

  const int t = threadIdx.x;
  const int h = t & 255;
  const int sg = t >> 8;       // which s-half (0: s 0..63, 1: s 64..127)
  const int wv = h >> 6;       // wave within half
  const int lane = h & 63;
  const int b = blockIdx.x;

  // stage x[b] into LDS (coalesced float4)
  {
    const float4* xg = (const float4*)(x + (size_t)b * Sn * Hn);
    float4* xl = (float4*)(&xs[0][0]);
    #pragma unroll
    for (int c = 0; c < 16; c++) xl[c * 512 + t] = xg[c * 512 + t];
  }
  const float alpha = alphap[0];
  const float wgt = lnw[h], bia = lnb[h];
  float kreg[24];
  #pragma unroll
  for (int q = 0; q < 24; q++) kreg[q] = kT[q * Hn + h];
  __syncthreads();

  // LN stats over h (256) for GRP s-rows; normalizes in place (no affine).
  auto reduce_ln_raw = [&](float (&q)[GRP]) {
    #pragma unroll
    for (int i = 0; i < GRP; i++) {
      float s1 = wave_red_sum(q[i]);
      float s2 = wave_red_sum(q[i] * q[i]);
      if (lane == 63) { red[sg][i][wv][0] = s1; red[sg][i][wv][1] = s2; }
    }
    __syncthreads();
    #pragma unroll
    for (int i = 0; i < GRP; i++) {
      const float4* rp = (const float4*)&red[sg][i][0][0];
      float4 p0 = rp[0], p1 = rp[1];
      float ts = p0.x + p0.z + p1.x + p1.z;
      float tq = p0.y + p0.w + p1.y + p1.w;
      float u = ts * (1.f / 256.f);
      float var = fmaf(-u, u, tq * (1.f / 256.f));
      float inv = 1.f / sqrtf(var + 1e-12f);
      q[i] = (q[i] - u) * inv;   // normalized, no affine
    }
    __syncthreads();
  };

  #pragma unroll 1   // keep the g-loop rolled: cross-iteration unrolling was inflating live ranges into scratch
  for (int g = 0; g < 8; g++) {
    const int s0 = sg * 64 + g * GRP;
    const bool edge = (s0 == 0) || (s0 + GRP == Sn);

    // x window rows s0-8 .. s0+15 (zero-padded like reference's u)
    float xw[GRP + 16];
    #pragma unroll
    for (int k = 0; k < GRP + 16; k++) {
      int r = s0 - 8 + k;
      xw[k] = (r >= 0 && r < Sn) ? xs[r][h] : 0.f;
    }

    // ---- four STFT branches, each layernormed (raw) then summed ----
    float semb[GRP];
    {
      float z[GRP];
      branch_accum<3, 0>(xw, kreg, s0, edge, z);
      reduce_ln_raw(z);
      #pragma unroll
      for (int i = 0; i < GRP; i++) semb[i] = z[i];
      branch_accum<5, 3>(xw, kreg, s0, edge, z);
      reduce_ln_raw(z);
      #pragma unroll
      for (int i = 0; i < GRP; i++) semb[i] += z[i];
      branch_accum<7, 8>(xw, kreg, s0, edge, z);
      reduce_ln_raw(z);
      #pragma unroll
      for (int i = 0; i < GRP; i++) semb[i] += z[i];
      branch_accum<9, 15>(xw, kreg, s0, edge, z);
      reduce_ln_raw(z);
      #pragma unroll
      for (int i = 0; i < GRP; i++) semb[i] += z[i];
    }

    // ---- global-fft branch: circular conv, block-Toeplitz 8x16 tiles ----
    float ff[GRP];
    #pragma unroll
    for (int i = 0; i < GRP; i++) ff[i] = 0.f;
    #pragma unroll 1   // keep rt-loop rolled too: bounds the cd/xr live window
    for (int rt = 0; rt < 8; rt++) {
      const int r0 = rt * 16;
      const int dbase = (s0 - r0) & 127;
      float cd[GRP + 15];
      #pragma unroll
      for (int k = 0; k < GRP + 15; k++)
        cd[k] = cT[((dbase + k - 15) & 127) * Hn + h];
      float xr[16];
      #pragma unroll
      for (int j = 0; j < 16; j++) xr[j] = xs[r0 + j][h];
      #pragma unroll
      for (int i = 0; i < GRP; i++) {
        #pragma unroll
        for (int j = 0; j < 16; j++)
          ff[i] = fmaf(cd[i - j + 15], xr[j], ff[i]);
      }
    }
    reduce_ln_raw(ff);

    // ---- mix + residual + final LN + store ----
    // sum_i LN_i = w*S + 4b ; LN_fft = w*F + b
    // mixed = w*(alpha*S + (1-alpha)*F) + b*(1+3*alpha) + x
    float fin[GRP];
    #pragma unroll
    for (int i = 0; i < GRP; i++) {
      float mixv = fmaf(alpha, semb[i] - ff[i], ff[i]);   // alpha*S + (1-alpha)*F
      fin[i] = fmaf(wgt, mixv, fmaf(3.f * alpha + 1.f, bia, xs[s0 + i][h]));
    }
    reduce_ln_raw(fin);
    #pragma unroll
    for (int i = 0; i < GRP; i++)
      out[((size_t)b * Sn + (s0 + i)) * Hn + h] = fmaf(fin[i], wgt, bia);
  }
}

extern "C" void kernel_launch(void* const* d_in, const int* in_sizes, int n_in,
                              void* d_out, int out_size, void* d_ws, size_t ws_size,
                              hipStream_t stream) {
  const float* x  = (const float*)d_in[0];
  const float* w3 = (const float*)d_in[1];
  const float* w5 = (const float*)d_in[2];
  const float* w7 = (const float*)d_in[3];
  const float* w9 = (const float*)d_in[4];
  const float* cw = (const float*)d_in[5];
  const float* al = (const float*)d_in[6];
  const float* lw = (const float*)d_in[7];
  const float* lb = (const float*)d_in[8];
  float* out = (float*)d_out;

  float* cT = (float*)d_ws;        // 128*256 floats
  float* kT = cT + Sn * Hn;        // 24*256 floats

  hipLaunchKernelGGL(k_setup, dim3(24), dim3(256), 0, stream, w3, w5, w7, w9, kT);
  hipLaunchKernelGGL(c_setup, dim3(Sn), dim3(256), 0, stream, cw, cT);
  hipLaunchKernelGGL(stft_main, dim3(Bn), dim3(512), 0, stream, x, cT, kT, lw, lb, al, out);
}

// Round 8
// 306.489 us; speedup vs baseline: 4.0449x; 1.3815x over previous
//
#include <hip/hip_runtime.h>
#include <math.h>

constexpr int Bn = 256, Sn = 128, Hn = 256;
constexpr int GRP = 8;   // 8 s-rows per group

// ---------------- setup: branch kernels k_i[h,tau] = irfft(w_i[h,:]) ----------------
// kT layout: [24][H]  slots: n=3 -> 0..2, n=5 -> 3..7, n=7 -> 8..14, n=9 -> 15..23
__global__ void k_setup(const float* __restrict__ w3, const float* __restrict__ w5,
                        const float* __restrict__ w7, const float* __restrict__ w9,
                        float* __restrict__ kT) {
  int t = blockIdx.x * blockDim.x + threadIdx.x;
  if (t >= 24 * Hn) return;
  int slot = t >> 8, h = t & 255;
  int n, base;
  const float* w;
  if (slot < 3)       { n = 3; base = 0;  w = w3; }
  else if (slot < 8)  { n = 5; base = 3;  w = w5; }
  else if (slot < 15) { n = 7; base = 8;  w = w7; }
  else                { n = 9; base = 15; w = w9; }
  int tau = slot - base;
  int F = (n + 1) / 2;
  float acc = w[(h * F) * 2];  // DC real (imag of DC cannot affect real output)
  for (int f = 1; f < F; f++) {
    float wr = w[(h * F + f) * 2 + 0];
    float wi = w[(h * F + f) * 2 + 1];
    int ft = (f * tau) % n;
    float ang = 6.28318530717958647692f * (float)ft / (float)n;
    float sv, cv;
    __sincosf(ang, &sv, &cv);
    acc += 2.f * (wr * cv - wi * sv);
  }
  kT[slot * Hn + h] = acc / (float)n;
}

// ---------------- setup: fft-branch circular kernel c[h,d] = irfft(cw[:,h]) ----------------
// cT layout: [128][H]  (d-major so lane reads over h are coalesced)
__global__ void c_setup(const float* __restrict__ cw, float* __restrict__ cT) {
  int t = blockIdx.x * blockDim.x + threadIdx.x;
  if (t >= Sn * Hn) return;
  int d = t >> 8, h = t & 255;
  float acc = cw[(0 * Hn + h) * 2 + 0] + ((d & 1) ? -1.f : 1.f) * cw[(64 * Hn + h) * 2 + 0];
  for (int k = 1; k < 64; k++) {
    float wr = cw[(k * Hn + h) * 2 + 0];
    float wi = cw[(k * Hn + h) * 2 + 1];
    int kd = (k * d) & 127;
    float ang = 6.28318530717958647692f * (float)kd * (1.f / 128.f);
    float sv, cv;
    __sincosf(ang, &sv, &cv);
    acc += 2.f * (wr * cv - wi * sv);
  }
  cT[d * Hn + h] = acc * (1.f / 128.f);
}

// ---------------- DPP wave reduction (VALU pipe, not DS) ----------------
template <int CTRL, int ROW_MASK>
__device__ __forceinline__ float dpp_add_f32(float v) {
  int p = __builtin_amdgcn_update_dpp(0, __float_as_int(v), CTRL, ROW_MASK, 0xf, true);
  return v + __int_as_float(p);
}
__device__ __forceinline__ float wave_red_sum(float v) {
  v = dpp_add_f32<0x111, 0xf>(v); // row_shr:1
  v = dpp_add_f32<0x112, 0xf>(v); // row_shr:2
  v = dpp_add_f32<0x114, 0xf>(v); // row_shr:4
  v = dpp_add_f32<0x118, 0xf>(v); // row_shr:8
  v = dpp_add_f32<0x142, 0xa>(v); // row_bcast:15
  v = dpp_add_f32<0x143, 0xc>(v); // row_bcast:31
  return v;                       // lane 63 = full wave sum
}

// ---------------- STFT branch accumulation (taps + overlap-add geometry) ----------------
// Branch kernel taps come from LDS (kTs[24][Hn]) instead of 24 permanently-live VGPRs.
template <int N, int BASE>
__device__ __attribute__((always_inline)) void branch_accum(
    const float (&xw)[GRP + 16], const float (&kTs)[24][Hn], int h,
    int s0, bool edge, float (&z)[GRP]) {
  constexpr int PAD = (N - 1) / 2;
  #pragma unroll
  for (int i = 0; i < GRP; i++) z[i] = 0.f;
  #pragma unroll
  for (int j = -(N - 1); j <= N - 1; j++) {
    const int m = (((-j) % N) + N) % N;   // folded at compile time under unroll
    const float kc = kTs[BASE + m][h];    // LDS broadcast-free, h-stride-1, conflict-free
    if (!edge) {
      const float ka = kc * ((float)(N - (j < 0 ? -j : j)) * (1.f / (float)N));
      #pragma unroll
      for (int i = 0; i < GRP; i++) z[i] = fmaf(ka, xw[8 + i + j], z[i]);
    } else {
      #pragma unroll
      for (int i = 0; i < GRP; i++) {
        int s = s0 + i, l = s + PAD;
        int tlo = max(0, max(l - Sn + 1, -j));
        int thi = min(N - 1, min(l, N - 1 - j));
        int cnt = max(0, thi - tlo + 1);
        int elo = max(0, l - Sn + 1), ehi = min(N - 1, l);
        float env = (float)(ehi - elo + 1);
        z[i] = fmaf(kc * ((float)cnt / env), xw[8 + i + j], z[i]);
      }
    }
  }
}

// ---------------- fused main kernel: one block per batch b ----------------
// LDS: xs 128K + kTs 24K + red 0.5K = 156K (<160K) -> 1 block/CU, 2 waves/SIMD.
// Register budget is hard-capped at 128 by the backend (R2/R5 evidence); moving
// kT to LDS drops the peak-phase live set to ~80 so everything fits -> no scratch.
__global__ __launch_bounds__(512) __attribute__((amdgpu_waves_per_eu(1, 2)))
void stft_main(
    const float* __restrict__ x, const float* __restrict__ cT,
    const float* __restrict__ kT, const float* __restrict__ lnw,
    const float* __restrict__ lnb, const float* __restrict__ alphap,
    float* __restrict__ out) {
  __shared__ float xs[Sn][Hn];          // 131072 B
  __shared__ float kTs[24][Hn];         // 24576 B
  __shared__ float red[2][GRP][4][2];   // 512 B  cross-wave LN partials

  const int t = threadIdx.x;
  const int h = t & 255;
  const int sg = t >> 8;       // which s-half (0: s 0..63, 1: s 64..127)
  const int wv = h >> 6;       // wave within half
  const int lane = h & 63;
  const int b = blockIdx.x;

  // stage x[b] into LDS (coalesced float4)
  {
    const float4* xg = (const float4*)(x + (size_t)b * Sn * Hn);
    float4* xl = (float4*)(&xs[0][0]);
    #pragma unroll
    for (int c = 0; c < 16; c++) xl[c * 512 + t] = xg[c * 512 + t];
  }
  // stage kT into LDS (24*256 floats = 1536 float4, 3 per thread)
  {
    const float4* kg = (const float4*)kT;
    float4* kl = (float4*)(&kTs[0][0]);
    #pragma unroll
    for (int c = 0; c < 3; c++) kl[c * 512 + t] = kg[c * 512 + t];
  }
  const float alpha = alphap[0];
  const float wgt = lnw[h], bia = lnb[h];
  __syncthreads();

  // LN stats over h (256) for GRP s-rows; normalizes in place (no affine).
  auto reduce_ln_raw = [&](float (&q)[GRP]) {
    #pragma unroll
    for (int i = 0; i < GRP; i++) {
      float s1 = wave_red_sum(q[i]);
      float s2 = wave_red_sum(q[i] * q[i]);
      if (lane == 63) { red[sg][i][wv][0] = s1; red[sg][i][wv][1] = s2; }
    }
    __syncthreads();
    #pragma unroll
    for (int i = 0; i < GRP; i++) {
      const float4* rp = (const float4*)&red[sg][i][0][0];
      float4 p0 = rp[0], p1 = rp[1];
      float ts = p0.x + p0.z + p1.x + p1.z;
      float tq = p0.y + p0.w + p1.y + p1.w;
      float u = ts * (1.f / 256.f);
      float var = fmaf(-u, u, tq * (1.f / 256.f));
      float inv = 1.f / sqrtf(var + 1e-12f);
      q[i] = (q[i] - u) * inv;   // normalized, no affine
    }
    __syncthreads();
  };

  #pragma unroll 1   // keep the g-loop rolled: unrolling inflated live ranges into scratch (R4)
  for (int g = 0; g < 8; g++) {
    const int s0 = sg * 64 + g * GRP;
    const bool edge = (s0 == 0) || (s0 + GRP == Sn);

    // x window rows s0-8 .. s0+15 (zero-padded like reference's u)
    float xw[GRP + 16];
    #pragma unroll
    for (int k = 0; k < GRP + 16; k++) {
      int r = s0 - 8 + k;
      xw[k] = (r >= 0 && r < Sn) ? xs[r][h] : 0.f;
    }

    // ---- four STFT branches, each layernormed (raw) then summed ----
    float semb[GRP];
    {
      float z[GRP];
      branch_accum<3, 0>(xw, kTs, h, s0, edge, z);
      reduce_ln_raw(z);
      #pragma unroll
      for (int i = 0; i < GRP; i++) semb[i] = z[i];
      branch_accum<5, 3>(xw, kTs, h, s0, edge, z);
      reduce_ln_raw(z);
      #pragma unroll
      for (int i = 0; i < GRP; i++) semb[i] += z[i];
      branch_accum<7, 8>(xw, kTs, h, s0, edge, z);
      reduce_ln_raw(z);
      #pragma unroll
      for (int i = 0; i < GRP; i++) semb[i] += z[i];
      branch_accum<9, 15>(xw, kTs, h, s0, edge, z);
      reduce_ln_raw(z);
      #pragma unroll
      for (int i = 0; i < GRP; i++) semb[i] += z[i];
    }

    // ---- global-fft branch: circular conv, block-Toeplitz 8x16 tiles ----
    float ff[GRP];
    #pragma unroll
    for (int i = 0; i < GRP; i++) ff[i] = 0.f;
    #pragma unroll 1   // keep rt-loop rolled: bounds the cd/xr live window
    for (int rt = 0; rt < 8; rt++) {
      const int r0 = rt * 16;
      const int dbase = (s0 - r0) & 127;
      float cd[GRP + 15];
      #pragma unroll
      for (int k = 0; k < GRP + 15; k++)
        cd[k] = cT[((dbase + k - 15) & 127) * Hn + h];
      float xr[16];
      #pragma unroll
      for (int j = 0; j < 16; j++) xr[j] = xs[r0 + j][h];
      #pragma unroll
      for (int i = 0; i < GRP; i++) {
        #pragma unroll
        for (int j = 0; j < 16; j++)
          ff[i] = fmaf(cd[i - j + 15], xr[j], ff[i]);
      }
    }
    reduce_ln_raw(ff);

    // ---- mix + residual + final LN + store ----
    // sum_i LN_i = w*S + 4b ; LN_fft = w*F + b
    // mixed = w*(alpha*S + (1-alpha)*F) + b*(1+3*alpha) + x
    float fin[GRP];
    #pragma unroll
    for (int i = 0; i < GRP; i++) {
      float mixv = fmaf(alpha, semb[i] - ff[i], ff[i]);   // alpha*S + (1-alpha)*F
      fin[i] = fmaf(wgt, mixv, fmaf(3.f * alpha + 1.f, bia, xs[s0 + i][h]));
    }
    reduce_ln_raw(fin);
    #pragma unroll
    for (int i = 0; i < GRP; i++)
      out[((size_t)b * Sn + (s0 + i)) * Hn + h] = fmaf(fin[i], wgt, bia);
  }
}

extern "C" void kernel_launch(void* const* d_in, const int* in_sizes, int n_in,
                              void* d_out, int out_size, void* d_ws, size_t ws_size,
                              hipStream_t stream) {
  const float* x  = (const float*)d_in[0];
  const float* w3 = (const float*)d_in[1];
  const float* w5 = (const float*)d_in[2];
  const float* w7 = (const float*)d_in[3];
  const float* w9 = (const float*)d_in[4];
  const float* cw = (const float*)d_in[5];
  const float* al = (const float*)d_in[6];
  const float* lw = (const float*)d_in[7];
  const float* lb = (const float*)d_in[8];
  float* out = (float*)d_out;

  float* cT = (float*)d_ws;        // 128*256 floats
  float* kT = cT + Sn * Hn;        // 24*256 floats

  hipLaunchKernelGGL(k_setup, dim3(24), dim3(256), 0, stream, w3, w5, w7, w9, kT);
  hipLaunchKernelGGL(c_setup, dim3(Sn), dim3(256), 0, stream, cw, cT);
  hipLaunchKernelGGL(stft_main, dim3(Bn), dim3(512), 0, stream, x, cT, kT, lw, lb, al, out);
}